// Round 1
// baseline (2390.083 us; speedup 1.0000x reference)
//
#include <hip/hip_runtime.h>

#define HSZ 32
#define TLEN 1024

__device__ __forceinline__ float rl_f(float v, int lane) {
    return __int_as_float(__builtin_amdgcn_readlane(__float_as_int(v), lane));
}
__device__ __forceinline__ float rcp_f(float x) { return __builtin_amdgcn_rcpf(x); }
__device__ __forceinline__ float exp2_f(float x) { return __builtin_amdgcn_exp2f(x); }

#define LOG2E 1.442695040888963f

__device__ __forceinline__ float sigmoid_f(float x) {
    return rcp_f(1.0f + exp2_f(-LOG2E * x));
}
__device__ __forceinline__ float tanh_fast(float x) {
    // 1 - 2/(exp(2x)+1); saturates correctly at +-inf
    return 1.0f - 2.0f * rcp_f(1.0f + exp2_f(2.0f * LOG2E * x));
}

// One wave (64 lanes) per batch element. Lane j handles gate rows j and j+64:
//   rows 0..31 = i, 32..63 = f, 64..95 = g, 96..127 = o
// so lane j<32 computes (i_j, g_j), lane j+32 computes (f_j, o_j); a single
// shfl_xor(32) pair recombines, both halves redundantly hold c_j, h_j.
// h broadcast via v_readlane -> SGPR, weights in per-lane VGPRs (192 f32).
__global__ __launch_bounds__(256, 2) void lstm2_fused(
    const float* __restrict__ x,
    const float* __restrict__ Wih0, const float* __restrict__ Whh0,
    const float* __restrict__ bih0, const float* __restrict__ bhh0,
    const float* __restrict__ Wih1, const float* __restrict__ Whh1,
    const float* __restrict__ bih1, const float* __restrict__ bhh1,
    const float* __restrict__ Wfc,  const float* __restrict__ bfc,
    float* __restrict__ out, int Tn)
{
    const int lane  = threadIdx.x & 63;
    const int wave  = threadIdx.x >> 6;
    const int b     = blockIdx.x * 4 + wave;
    const int j     = lane & 31;
    const bool lower = lane < 32;
    const int r0 = lane;        // row j      (i for j<32, f for j>=32)
    const int r1 = lane + 64;   // row j+64   (g for j<32, o for j>=32)

    // ---- load weights into registers (one-time) ----
    float w0a[HSZ], w0b[HSZ], wi1a[HSZ], wi1b[HSZ], w1a[HSZ], w1b[HSZ];
    #pragma unroll
    for (int k4 = 0; k4 < HSZ / 4; ++k4) {
        float4 t0 = *(const float4*)(Whh0 + (size_t)r0 * HSZ + 4 * k4);
        float4 t1 = *(const float4*)(Whh0 + (size_t)r1 * HSZ + 4 * k4);
        float4 t2 = *(const float4*)(Wih1 + (size_t)r0 * HSZ + 4 * k4);
        float4 t3 = *(const float4*)(Wih1 + (size_t)r1 * HSZ + 4 * k4);
        float4 t4 = *(const float4*)(Whh1 + (size_t)r0 * HSZ + 4 * k4);
        float4 t5 = *(const float4*)(Whh1 + (size_t)r1 * HSZ + 4 * k4);
        w0a [4*k4+0] = t0.x; w0a [4*k4+1] = t0.y; w0a [4*k4+2] = t0.z; w0a [4*k4+3] = t0.w;
        w0b [4*k4+0] = t1.x; w0b [4*k4+1] = t1.y; w0b [4*k4+2] = t1.z; w0b [4*k4+3] = t1.w;
        wi1a[4*k4+0] = t2.x; wi1a[4*k4+1] = t2.y; wi1a[4*k4+2] = t2.z; wi1a[4*k4+3] = t2.w;
        wi1b[4*k4+0] = t3.x; wi1b[4*k4+1] = t3.y; wi1b[4*k4+2] = t3.z; wi1b[4*k4+3] = t3.w;
        w1a [4*k4+0] = t4.x; w1a [4*k4+1] = t4.y; w1a [4*k4+2] = t4.z; w1a [4*k4+3] = t4.w;
        w1b [4*k4+0] = t5.x; w1b [4*k4+1] = t5.y; w1b [4*k4+2] = t5.z; w1b [4*k4+3] = t5.w;
    }
    const float b0a = bih0[r0] + bhh0[r0];
    const float b0b = bih0[r1] + bhh0[r1];
    const float b1a = bih1[r0] + bhh1[r0];
    const float b1b = bih1[r1] + bhh1[r1];
    const float wxa = Wih0[r0];   // Wih0 is (128,1)
    const float wxb = Wih0[r1];
    const float wfc = lower ? Wfc[j] : 0.0f;
    const float bfc0 = bfc[0];

    // ---- state ----
    float c0v = 0.0f, h0v = 0.0f, c1v = 0.0f, h1v = 0.0f;
    float h0s[HSZ], h1s[HSZ];   // wave-uniform broadcast copies (SGPRs)
    #pragma unroll
    for (int k = 0; k < HSZ; ++k) { h0s[k] = 0.0f; h1s[k] = 0.0f; }

#define GATE_UPDATE(A0, A1, CVAR, HVAR)                                    \
    {                                                                      \
        float act0 = sigmoid_f(A0);                                        \
        float u    = lower ? (A1) : 0.5f * (A1);                           \
        float th   = tanh_fast(u);                                         \
        float act1 = lower ? th : fmaf(0.5f, th, 0.5f);                    \
        float sw0  = __shfl_xor(act0, 32, 64);                             \
        float sw1  = __shfl_xor(act1, 32, 64);                             \
        float fv = lower ? sw0  : act0;                                    \
        float iv = lower ? act0 : sw0;                                     \
        float gv = lower ? act1 : sw1;                                     \
        float ov = lower ? sw1  : act1;                                    \
        CVAR = fmaf(fv, CVAR, iv * gv);                                    \
        HVAR = ov * tanh_fast(CVAR);                                       \
    }

    const float* xb = x + (size_t)b * Tn;
    for (int t = 0; t < Tn; ++t) {
        const float xt = xb[t];   // wave-uniform -> s_load

        // ---- layer 0 ----
        float a0 = fmaf(xt, wxa, b0a);
        float a1 = fmaf(xt, wxb, b0b);
        #pragma unroll
        for (int k = 0; k < HSZ; ++k) {
            a0 = fmaf(w0a[k], h0s[k], a0);
            a1 = fmaf(w0b[k], h0s[k], a1);
        }
        GATE_UPDATE(a0, a1, c0v, h0v);
        #pragma unroll
        for (int k = 0; k < HSZ; ++k) h0s[k] = rl_f(h0v, k);

        // ---- layer 1 ----
        float d0 = b1a;
        float d1 = b1b;
        #pragma unroll
        for (int k = 0; k < HSZ; ++k) {
            d0 = fmaf(wi1a[k], h0s[k], d0);
            d1 = fmaf(wi1b[k], h0s[k], d1);
            d0 = fmaf(w1a[k], h1s[k], d0);
            d1 = fmaf(w1b[k], h1s[k], d1);
        }
        GATE_UPDATE(d0, d1, c1v, h1v);
        #pragma unroll
        for (int k = 0; k < HSZ; ++k) h1s[k] = rl_f(h1v, k);
    }

    // ---- FC head: out[b] = dot(h1, Wfc) + bfc ----
    float p = h1v * wfc;          // upper lanes contribute 0 (wfc==0)
    #pragma unroll
    for (int off = 1; off < 64; off <<= 1)
        p += __shfl_xor(p, off, 64);
    if (lane == 0) out[b] = p + bfc0;
#undef GATE_UPDATE
}

extern "C" void kernel_launch(void* const* d_in, const int* in_sizes, int n_in,
                              void* d_out, int out_size, void* d_ws, size_t ws_size,
                              hipStream_t stream) {
    const float* x    = (const float*)d_in[0];
    const float* Wih0 = (const float*)d_in[1];
    const float* Whh0 = (const float*)d_in[2];
    const float* bih0 = (const float*)d_in[3];
    const float* bhh0 = (const float*)d_in[4];
    const float* Wih1 = (const float*)d_in[5];
    const float* Whh1 = (const float*)d_in[6];
    const float* bih1 = (const float*)d_in[7];
    const float* bhh1 = (const float*)d_in[8];
    const float* Wfc  = (const float*)d_in[9];
    const float* bfc  = (const float*)d_in[10];
    float* out = (float*)d_out;

    const int Tn = TLEN;
    const int B  = in_sizes[0] / Tn;   // x is (B, T, 1)

    dim3 block(256);
    dim3 grid(B / 4);                  // 4 waves per block, 1 batch element per wave
    hipLaunchKernelGGL(lstm2_fused, grid, block, 0, stream,
                       x, Wih0, Whh0, bih0, bhh0, Wih1, Whh1, bih1, bhh1,
                       Wfc, bfc, out, Tn);
}

// Round 2
// 847.284 us; speedup vs baseline: 2.8209x; 2.8209x over previous
//
#include <hip/hip_runtime.h>

#define HSZ    32
#define TLEN   1024
#define XCHUNK 64
#define GS     17     // gates LDS row stride (padded to break 4-way conflicts)

typedef _Float16 half8 __attribute__((ext_vector_type(8)));
typedef float    f32x4 __attribute__((ext_vector_type(4)));

__device__ __forceinline__ float rcp_f(float x){ return __builtin_amdgcn_rcpf(x); }
__device__ __forceinline__ float exp2_f(float x){ return __builtin_amdgcn_exp2f(x); }
#define LOG2E 1.442695040888963f
__device__ __forceinline__ float sigmoid_f(float x){ return rcp_f(1.0f + exp2_f(-LOG2E*x)); }
__device__ __forceinline__ float tanh_fast(float x){ return 1.0f - 2.0f*rcp_f(1.0f + exp2_f(2.0f*LOG2E*x)); }

__device__ __forceinline__ f32x4 mfma16(half8 a, half8 b, f32x4 c){
  return __builtin_amdgcn_mfma_f32_16x16x32_f16(a, b, c, 0, 0, 0);
}

// Workgroup = 8 waves = one 16-batch tile. Wave w owns gate rows 16w..16w+15.
// Gate rows: 0..31 = i, 32..63 = f, 64..95 = g, 96..127 = o (jnp.split order).
//
// MFMA fragment conventions (gfx950 16x16x32, guide-verified D layout):
//   D: col = lane&15, row = (lane>>4)*4 + j            (j = 0..3, f32)
//   A: row = lane&15, k-slot (g=lane>>4, j=0..7)       (8 f16)
//   B: col = lane&15, k-slot (g=lane>>4, j=0..7)       (8 f16)
// We pack A and B with OUR OWN k-order k = 8g + j on both sides; the product
// is invariant to the hardware's actual (symmetric) k permutation.
//
// h exchange: f16 hi/lo planes, layout [col][k] (32 f16 = 64B per col), with
// a 16B-line XOR swizzle (line ^= col&3) so that the 64 b16 scatter-writes
// spread across banks while each lane's ds_read_b128 still lands on its
// 8-element k-run:  write k=rs at line (rs>>3)^(col&3), read line g^(col&3).
__global__ __launch_bounds__(512, 2) void lstm2_mfma(
    const float* __restrict__ x,
    const float* __restrict__ Wih0, const float* __restrict__ Whh0,
    const float* __restrict__ bih0, const float* __restrict__ bhh0,
    const float* __restrict__ Wih1, const float* __restrict__ Whh1,
    const float* __restrict__ bih1, const float* __restrict__ bhh1,
    const float* __restrict__ Wfc,  const float* __restrict__ bfc,
    float* __restrict__ out, int Tn)
{
  __shared__ float gates0[128*GS];                 // layer-0 activated gates (f32)
  __shared__ float gates1[128*GS];                 // layer-1 activated gates (f32)
  __shared__ __align__(16) _Float16 ph0hi[16*32];  // h0 hi/lo f16 planes [col][k]
  __shared__ __align__(16) _Float16 ph0lo[16*32];
  __shared__ __align__(16) _Float16 ph1hi[16*32];
  __shared__ __align__(16) _Float16 ph1lo[16*32];
  __shared__ float xbuf[XCHUNK*16];                // x chunk, [t&63][batch-col]

  const int tid = threadIdx.x;
  const int w   = tid >> 6;        // wave 0..7 -> gate-row tile
  const int l   = tid & 63;
  const int col = l & 15;          // batch col / A row (within tile)
  const int g   = l >> 4;          // k-group 0..3
  const int b0  = blockIdx.x * 16;
  const int q   = w >> 1;          // 0:i(sig) 1:f(sig) 2:g(tanh) 3:o(sig)

  // ---- A fragments: W rows 16w + (l&15), k = 8g+j ; split f32 -> f16 hi+lo ----
  const int arow = 16*w + col;
  half8 Ahh0h, Ahh0l, Aih1h, Aih1l, Ahh1h, Ahh1l;
  {
    const float* p0 = Whh0 + arow*HSZ + 8*g;
    const float* p1 = Wih1 + arow*HSZ + 8*g;
    const float* p2 = Whh1 + arow*HSZ + 8*g;
    #pragma unroll
    for (int j = 0; j < 8; ++j){
      float v0 = p0[j], v1 = p1[j], v2 = p2[j];
      _Float16 a = (_Float16)v0; Ahh0h[j] = a; Ahh0l[j] = (_Float16)(v0 - (float)a);
      _Float16 b = (_Float16)v1; Aih1h[j] = b; Aih1l[j] = (_Float16)(v1 - (float)b);
      _Float16 c = (_Float16)v2; Ahh1h[j] = c; Ahh1l[j] = (_Float16)(v2 - (float)c);
    }
  }
  // per-lane D-row constants: rows 16w + 4g + j
  float wx[4], bs0[4], bs1[4];
  #pragma unroll
  for (int j = 0; j < 4; ++j){
    int r  = 16*w + 4*g + j;
    wx[j]  = Wih0[r];                 // Wih0 is (128,1)
    bs0[j] = bih0[r] + bhh0[r];
    bs1[j] = bih1[r] + bhh1[r];
  }

  const int rs = 4*w + g;                                        // state row this lane updates
  const int wr_off = col*32 + ((((rs>>3) ^ (col&3))) << 3) + (rs&7);  // f16 units
  const int rd_off = col*32 + ((g ^ (col&3)) << 3);                   // f16 units

  // ---- init: zero h planes, stage x chunk 0 ----
  ph0hi[tid] = (_Float16)0.0f; ph0lo[tid] = (_Float16)0.0f;
  ph1hi[tid] = (_Float16)0.0f; ph1lo[tid] = (_Float16)0.0f;
  #pragma unroll
  for (int s = 0; s < 2; ++s){
    int tt = 8*w + g + 4*s;          // 8 t-slots per wave, bank-friendly
    xbuf[tt*16 + col] = x[(size_t)(b0 + col)*Tn + tt];
  }
  __syncthreads();

  half8 bh0h = {}; half8 bh0l = {};  // h0(-1) = 0 fragments (carried)
  float c0 = 0.f, c1 = 0.f, h1last = 0.f;
  const f32x4 zero4 = {0.f, 0.f, 0.f, 0.f};

  for (int t = 0; t < Tn; ++t){
    // ================= layer 0 =================
    float xv = xbuf[(t & (XCHUNK-1))*16 + col];
    f32x4 accA, accB;
    #pragma unroll
    for (int j = 0; j < 4; ++j) accA[j] = fmaf(xv, wx[j], bs0[j]);
    accB = zero4;
    accA = mfma16(Ahh0h, bh0h, accA);          // main
    accB = mfma16(Ahh0h, bh0l, accB);          // cross terms (separate chain)
    accB = mfma16(Ahh0l, bh0h, accB);
    f32x4 pre0;
    #pragma unroll
    for (int j = 0; j < 4; ++j) pre0[j] = accA[j] + accB[j];
    float ga[4];
    if (q == 2){
      #pragma unroll
      for (int j = 0; j < 4; ++j) ga[j] = tanh_fast(pre0[j]);
    } else {
      #pragma unroll
      for (int j = 0; j < 4; ++j) ga[j] = sigmoid_f(pre0[j]);
    }
    #pragma unroll
    for (int j = 0; j < 4; ++j) gates0[(16*w + 4*g + j)*GS + col] = ga[j];
    __syncthreads();                                   // BAR-a
    // h1(t-1) fragments (writes from end of step t-1 are drained at BAR-a)
    half8 bh1h = *(const half8*)&ph1hi[rd_off];
    half8 bh1l = *(const half8*)&ph1lo[rd_off];
    // restage next x chunk inside the [BAR-a, BAR-b] window
    if ((t & (XCHUNK-1)) == (XCHUNK-1) && t + 1 < Tn){
      int t0 = t + 1;
      #pragma unroll
      for (int s = 0; s < 2; ++s){
        int tt = 8*w + g + 4*s;
        xbuf[tt*16 + col] = x[(size_t)(b0 + col)*Tn + t0 + tt];
      }
    }
    // c0/h0 update: one state row per lane
    float iv = gates0[(  0 + rs)*GS + col];
    float fv = gates0[( 32 + rs)*GS + col];
    float gv = gates0[( 64 + rs)*GS + col];
    float ov = gates0[( 96 + rs)*GS + col];
    c0 = fmaf(fv, c0, iv*gv);
    float h0v = ov * tanh_fast(c0);
    _Float16 hh = (_Float16)h0v;
    ph0hi[wr_off] = hh;
    ph0lo[wr_off] = (_Float16)(h0v - (float)hh);
    __syncthreads();                                   // BAR-b
    // ================= layer 1 =================
    bh0h = *(const half8*)&ph0hi[rd_off];              // h0(t) fragments (kept for next L0)
    bh0l = *(const half8*)&ph0lo[rd_off];
    f32x4 a1, a2;
    #pragma unroll
    for (int j = 0; j < 4; ++j) a1[j] = bs1[j];
    a1 = mfma16(Ahh1h, bh1h, a1);                      // h1 terms first (frags ready early)
    a1 = mfma16(Ahh1h, bh1l, a1);
    a1 = mfma16(Ahh1l, bh1h, a1);
    a2 = zero4;
    a2 = mfma16(Aih1h, bh0h, a2);                      // h0 terms once read lands
    a2 = mfma16(Aih1h, bh0l, a2);
    a2 = mfma16(Aih1l, bh0h, a2);
    f32x4 pre1;
    #pragma unroll
    for (int j = 0; j < 4; ++j) pre1[j] = a1[j] + a2[j];
    float gb[4];
    if (q == 2){
      #pragma unroll
      for (int j = 0; j < 4; ++j) gb[j] = tanh_fast(pre1[j]);
    } else {
      #pragma unroll
      for (int j = 0; j < 4; ++j) gb[j] = sigmoid_f(pre1[j]);
    }
    #pragma unroll
    for (int j = 0; j < 4; ++j) gates1[(16*w + 4*g + j)*GS + col] = gb[j];
    __syncthreads();                                   // BAR-c
    float i1 = gates1[(  0 + rs)*GS + col];
    float f1 = gates1[( 32 + rs)*GS + col];
    float g1 = gates1[( 64 + rs)*GS + col];
    float o1 = gates1[( 96 + rs)*GS + col];
    c1 = fmaf(f1, c1, i1*g1);
    float h1v = o1 * tanh_fast(c1);
    h1last = h1v;
    _Float16 jh = (_Float16)h1v;
    ph1hi[wr_off] = jh;
    ph1lo[wr_off] = (_Float16)(h1v - (float)jh);
    // (visibility for next step's bh1 read is covered by BAR-a)
  }

  // ---- FC head: out[b0+c] = dot(h1_final[:, c], Wfc) + bfc ----
  gates0[rs*GS + col] = h1last;     // all 512 lanes cover 32 rows x 16 cols
  __syncthreads();
  if (tid < 16){
    float s = bfc[0];
    #pragma unroll 8
    for (int k = 0; k < HSZ; ++k) s = fmaf(gates0[k*GS + tid], Wfc[k], s);
    out[b0 + tid] = s;
  }
}

extern "C" void kernel_launch(void* const* d_in, const int* in_sizes, int n_in,
                              void* d_out, int out_size, void* d_ws, size_t ws_size,
                              hipStream_t stream) {
  const float* x    = (const float*)d_in[0];
  const float* Wih0 = (const float*)d_in[1];
  const float* Whh0 = (const float*)d_in[2];
  const float* bih0 = (const float*)d_in[3];
  const float* bhh0 = (const float*)d_in[4];
  const float* Wih1 = (const float*)d_in[5];
  const float* Whh1 = (const float*)d_in[6];
  const float* bih1 = (const float*)d_in[7];
  const float* bhh1 = (const float*)d_in[8];
  const float* Wfc  = (const float*)d_in[9];
  const float* bfc  = (const float*)d_in[10];
  float* out = (float*)d_out;

  const int Tn = TLEN;
  const int B  = in_sizes[0] / Tn;      // x is (B, T, 1)

  dim3 block(512);
  dim3 grid(B / 16);                    // one 16-batch tile per workgroup
  hipLaunchKernelGGL(lstm2_mfma, grid, block, 0, stream,
                     x, Wih0, Whh0, bih0, bhh0, Wih1, Whh1, bih1, bhh1,
                     Wfc, bfc, out, Tn);
}

// Round 3
// 591.868 us; speedup vs baseline: 4.0382x; 1.4315x over previous
//
#include <hip/hip_runtime.h>

#define HSZ  32
#define TLEN 1024
#define PK   40          // f16 stride per col inside an h plane (pad: even bank spread)

typedef _Float16 half8 __attribute__((ext_vector_type(8)));
typedef float    f32x4 __attribute__((ext_vector_type(4)));

__device__ __forceinline__ float rcp_f(float x){ return __builtin_amdgcn_rcpf(x); }
__device__ __forceinline__ float exp2_f(float x){ return __builtin_amdgcn_exp2f(x); }
#define LOG2E 1.442695040888963f
__device__ __forceinline__ float sigmoid_f(float x){ return rcp_f(1.0f + exp2_f(-LOG2E*x)); }
__device__ __forceinline__ float tanh_fast(float x){ return 1.0f - 2.0f*rcp_f(1.0f + exp2_f(2.0f*LOG2E*x)); }
__device__ __forceinline__ f32x4 mfma16(half8 a, half8 b, f32x4 c){
  return __builtin_amdgcn_mfma_f32_16x16x32_f16(a, b, c, 0, 0, 0);
}

// 8 waves = one 16-batch tile. PERMUTED A-row trick: A tile-row r is loaded from
// physical gate row P(r) = 32*(r&3) + 4w + (r>>2). Since D row = 4*(lane>>4)+j,
// lane (g=lane>>4, col=lane&15) register j holds gate type j (i,f,g,o in
// jnp.split order) of state s = 4w+g, batch col. The whole gate quad is IN-LANE:
// no gates LDS round-trip, no transpose, gate type = compile-time reg index.
// Only h crosses waves: hi/lo f16 planes [col][PK], parity double-buffered ->
// ONE barrier per step. x is per-lane global prefetch (L1/L2 resident).
__global__ __launch_bounds__(512, 2) void lstm2_mfma3(
    const float* __restrict__ x,
    const float* __restrict__ Wih0, const float* __restrict__ Whh0,
    const float* __restrict__ bih0, const float* __restrict__ bhh0,
    const float* __restrict__ Wih1, const float* __restrict__ Whh1,
    const float* __restrict__ bih1, const float* __restrict__ bhh1,
    const float* __restrict__ Wfc,  const float* __restrict__ bfc,
    float* __restrict__ out, int Tn)
{
  // [parity][layer h0/h1][hi/lo][col*PK + k]
  __shared__ __align__(16) _Float16 hP[2][2][2][16*PK];

  const int tid = threadIdx.x;
  const int w   = tid >> 6;       // wave: owns states 4w..4w+3
  const int l   = tid & 63;
  const int col = l & 15;         // batch col (B/D) == A tile-row index
  const int g   = l >> 4;         // k-group (A/B) == D row-group
  const int s   = 4*w + g;        // state row this lane owns
  const int b0  = blockIdx.x * 16;

  // ---- A fragments, permuted rows, split f32 -> f16 hi+lo ----
  const int prow = 32*(col & 3) + 4*w + (col >> 2);
  half8 A0h, A0l, AIh, AIl, AHh, AHl;
  {
    const float* p0 = Whh0 + prow*HSZ + 8*g;
    const float* p1 = Wih1 + prow*HSZ + 8*g;
    const float* p2 = Whh1 + prow*HSZ + 8*g;
    #pragma unroll
    for (int j = 0; j < 8; ++j){
      float v0 = p0[j], v1 = p1[j], v2 = p2[j];
      _Float16 a = (_Float16)v0; A0h[j] = a; A0l[j] = (_Float16)(v0 - (float)a);
      _Float16 b = (_Float16)v1; AIh[j] = b; AIl[j] = (_Float16)(v1 - (float)b);
      _Float16 c = (_Float16)v2; AHh[j] = c; AHl[j] = (_Float16)(v2 - (float)c);
    }
  }
  // D reg j = physical row 32j + s
  float wx[4], bs0[4], bs1[4];
  #pragma unroll
  for (int j = 0; j < 4; ++j){
    int r  = 32*j + s;
    wx[j]  = Wih0[r];
    bs0[j] = bih0[r] + bhh0[r];
    bs1[j] = bih1[r] + bhh1[r];
  }

  const int wr = col*PK + s;      // f16 write offset in a plane
  const int rd = col*PK + 8*g;    // f16 read offset (16B-aligned b128)

  // zero planes (t=0 reads h1(-1)=0 from parity 1)
  for (int i = tid; i < 2*2*2*16*PK; i += 512) (&hP[0][0][0][0])[i] = (_Float16)0.0f;
  __syncthreads();

  half8 Bh0h = {}, Bh0l = {};     // h0(t-1) frags (start at 0)
  half8 Bh1h, Bh1l;
  float c0 = 0.f, c1 = 0.f, h1v = 0.f;
  const float* xp = x + (size_t)(b0 + col) * Tn;
  float xv = xp[0];

  for (int t = 0; t < Tn; ++t){
    const int p = t & 1, q = p ^ 1;
    const int tn = (t + 1 < Tn) ? t + 1 : Tn - 1;
    float xn = xp[tn];                          // prefetch, used next step

    // ================= layer 0 =================
    f32x4 accA, accB = {0.f, 0.f, 0.f, 0.f};
    #pragma unroll
    for (int j = 0; j < 4; ++j) accA[j] = fmaf(xv, wx[j], bs0[j]);
    accA = mfma16(A0h, Bh0h, accA);
    accB = mfma16(A0h, Bh0l, accB);
    accB = mfma16(A0l, Bh0h, accB);
    float i0 = sigmoid_f(accA[0] + accB[0]);
    float f0 = sigmoid_f(accA[1] + accB[1]);
    float g0 = tanh_fast(accA[2] + accB[2]);
    float o0 = sigmoid_f(accA[3] + accB[3]);
    c0 = fmaf(f0, c0, i0 * g0);
    float h0v = o0 * tanh_fast(c0);
    _Float16 hh0 = (_Float16)h0v;
    hP[p][0][0][wr] = hh0;
    hP[p][0][1][wr] = (_Float16)(h0v - (float)hh0);

    __syncthreads();                             // the ONLY barrier per step

    Bh0h = *(const half8*)&hP[p][0][0][rd];      // h0(t)
    Bh0l = *(const half8*)&hP[p][0][1][rd];
    Bh1h = *(const half8*)&hP[q][1][0][rd];      // h1(t-1)
    Bh1l = *(const half8*)&hP[q][1][1][rd];

    // ================= layer 1 =================
    f32x4 a1, a2 = {0.f,0.f,0.f,0.f}, a3 = {0.f,0.f,0.f,0.f};
    #pragma unroll
    for (int j = 0; j < 4; ++j) a1[j] = bs1[j];
    a3 = mfma16(AIh, Bh0h, a3);                  // chains of 2 (short latency)
    a3 = mfma16(AIl, Bh0h, a3);
    a2 = mfma16(AIh, Bh0l, a2);
    a1 = mfma16(AHh, Bh1h, a1);
    a1 = mfma16(AHl, Bh1h, a1);
    a2 = mfma16(AHh, Bh1l, a2);
    float i1 = sigmoid_f(a1[0] + a2[0] + a3[0]);
    float f1 = sigmoid_f(a1[1] + a2[1] + a3[1]);
    float g1 = tanh_fast(a1[2] + a2[2] + a3[2]);
    float o1 = sigmoid_f(a1[3] + a2[3] + a3[3]);
    c1 = fmaf(f1, c1, i1 * g1);
    h1v = o1 * tanh_fast(c1);
    _Float16 hh1 = (_Float16)h1v;
    hP[p][1][0][wr] = hh1;
    hP[p][1][1][wr] = (_Float16)(h1v - (float)hh1);
    // no end barrier: next step's barrier separates every reuse (parity dbuf)

    xv = xn;
  }

  // ---- FC head ----
  __syncthreads();
  float* sc = (float*)&hP[0][0][0][0];           // reuse LDS as f32 scratch
  sc[s*17 + col] = h1v;
  __syncthreads();
  if (tid < 16){
    float acc = bfc[0];
    #pragma unroll 8
    for (int k = 0; k < HSZ; ++k) acc = fmaf(sc[k*17 + tid], Wfc[k], acc);
    out[b0 + tid] = acc;
  }
}

extern "C" void kernel_launch(void* const* d_in, const int* in_sizes, int n_in,
                              void* d_out, int out_size, void* d_ws, size_t ws_size,
                              hipStream_t stream) {
  const float* x    = (const float*)d_in[0];
  const float* Wih0 = (const float*)d_in[1];
  const float* Whh0 = (const float*)d_in[2];
  const float* bih0 = (const float*)d_in[3];
  const float* bhh0 = (const float*)d_in[4];
  const float* Wih1 = (const float*)d_in[5];
  const float* Whh1 = (const float*)d_in[6];
  const float* bih1 = (const float*)d_in[7];
  const float* bhh1 = (const float*)d_in[8];
  const float* Wfc  = (const float*)d_in[9];
  const float* bfc  = (const float*)d_in[10];
  float* out = (float*)d_out;

  const int Tn = TLEN;
  const int B  = in_sizes[0] / Tn;     // x is (B, T, 1)

  dim3 block(512);
  dim3 grid(B / 16);
  hipLaunchKernelGGL(lstm2_mfma3, grid, block, 0, stream,
                     x, Wih0, Whh0, bih0, bhh0, Wih1, Whh1, bih1, bhh1,
                     Wfc, bfc, out, Tn);
}

// Round 4
// 576.502 us; speedup vs baseline: 4.1458x; 1.0267x over previous
//
#include <hip/hip_runtime.h>

#define HSZ  32
#define TLEN 1024
#define CS   36   // u32 stride per col in an h plane (144 B: 16B-aligned, conflict-free)

typedef _Float16 half8 __attribute__((ext_vector_type(8)));
typedef float    f32x4 __attribute__((ext_vector_type(4)));

__device__ __forceinline__ float rcp_f(float x){ return __builtin_amdgcn_rcpf(x); }
__device__ __forceinline__ float exp2_f(float x){ return __builtin_amdgcn_exp2f(x); }
#define LOG2E 1.442695040888963f
__device__ __forceinline__ float sigmoid_f(float x){ return rcp_f(1.0f + exp2_f(-LOG2E*x)); }
__device__ __forceinline__ float tanh_fast(float x){ return 1.0f - 2.0f*rcp_f(1.0f + exp2_f(2.0f*LOG2E*x)); }
__device__ __forceinline__ f32x4 mfma16(half8 a, half8 b, f32x4 c){
  return __builtin_amdgcn_mfma_f32_16x16x32_f16(a, b, c, 0, 0, 0);
}

// Split a f32 into (hi,lo) f16 pair packed in one u32 (hi in low 16 bits).
__device__ __forceinline__ unsigned int packsplit(float v){
  _Float16 hi = (_Float16)v;
  _Float16 lo = (_Float16)(v - (float)hi);
  unsigned short a = __builtin_bit_cast(unsigned short, hi);
  unsigned short b = __builtin_bit_cast(unsigned short, lo);
  return (unsigned int)a | ((unsigned int)b << 16);
}

// 8 waves = one 16-batch tile; wave w owns states 4w..4w+3 (permuted A-row trick:
// A tile-row r loads physical gate row 32*(r&3)+4w+(r>>2), so lane (g,col) D-regs
// j=0..3 are gates (i,f,g,o) of state s=4w+g -- whole quad in-lane, no gate LDS).
//
// EXACT interleaved split: h stored as u32 = (f16 hi, f16 lo). MFMA slot pairs:
//   A_I = (wh,wl) interleaved, A_S = (wl,wh) swapped.
//   mfma(A_I,B) + mfma(A_S,B) = sum_k (wh+wl)*(hh+hl)  -- exact split product.
// Each MFMA covers 16 real k -> 2 k-halves per matvec. Per step: 12 MFMA,
// 4 ds_read_b128 (conflict-free @ stride 144B), 2 ds_write_b32 (pure 2-way),
// ONE barrier. x loaded as float4 per 4 steps, prefetched a quad ahead.
__global__ __launch_bounds__(512, 2) void lstm2_mfma4(
    const float* __restrict__ x,
    const float* __restrict__ Wih0, const float* __restrict__ Whh0,
    const float* __restrict__ bih0, const float* __restrict__ bhh0,
    const float* __restrict__ Wih1, const float* __restrict__ Whh1,
    const float* __restrict__ bih1, const float* __restrict__ bhh1,
    const float* __restrict__ Wfc,  const float* __restrict__ bfc,
    float* __restrict__ out, int Tn)
{
  __shared__ __align__(16) unsigned int hw[2][2][16*CS];  // [parity][layer][col*CS + k]

  const int tid = threadIdx.x;
  const int w   = tid >> 6;
  const int l   = tid & 63;
  const int col = l & 15;        // batch col == A tile-row index
  const int g   = l >> 4;        // k-group == D row-group
  const int s   = 4*w + g;       // state this lane owns
  const int b0  = blockIdx.x * 16;

  // ---- A fragments (interleaved + swapped), permuted rows ----
  const int prow = 32*(col & 3) + 4*w + (col >> 2);
  half8 A0I0, A0I1, A0S0, A0S1;   // Whh0
  half8 AII0, AII1, AIS0, AIS1;   // Wih1
  half8 AHI0, AHI1, AHS0, AHS1;   // Whh1
  {
    const float* rows[3] = { Whh0 + prow*HSZ, Wih1 + prow*HSZ, Whh1 + prow*HSZ };
    half8* I0[3] = { &A0I0, &AII0, &AHI0 };
    half8* I1[3] = { &A0I1, &AII1, &AHI1 };
    half8* S0[3] = { &A0S0, &AIS0, &AHS0 };
    half8* S1[3] = { &A0S1, &AIS1, &AHS1 };
    #pragma unroll
    for (int m3 = 0; m3 < 3; ++m3){
      #pragma unroll
      for (int H = 0; H < 2; ++H){
        half8& I = H ? *I1[m3] : *I0[m3];
        half8& S = H ? *S1[m3] : *S0[m3];
        #pragma unroll
        for (int m = 0; m < 4; ++m){
          float v = rows[m3][16*H + 4*g + m];
          _Float16 hi = (_Float16)v;
          _Float16 lo = (_Float16)(v - (float)hi);
          I[2*m] = hi; I[2*m+1] = lo;
          S[2*m] = lo; S[2*m+1] = hi;
        }
      }
    }
  }
  // D reg j = physical gate row 32j + s
  float wx[4], bs0[4];
  f32x4 bias1;
  #pragma unroll
  for (int j = 0; j < 4; ++j){
    int r   = 32*j + s;
    wx[j]   = Wih0[r];
    bs0[j]  = bih0[r] + bhh0[r];
    bias1[j]= bih1[r] + bhh1[r];
  }

  const int wrI = col*CS + s;        // u32 index for this lane's h write
  const int rdI = col*CS + 4*g;      // u32 index of b128 read (half 0); +16 for half 1

  for (int i = tid; i < 2*2*16*CS; i += 512) (&hw[0][0][0])[i] = 0u;
  __syncthreads();

  half8 B00 = {}; half8 B01 = {};    // h0(t-1) fragments, start at 0
  float c0 = 0.f, c1 = 0.f, h1v = 0.f;

#define STEP(P, XV)                                                        \
  {                                                                        \
    f32x4 e;                                                               \
    e[0] = fmaf((XV), wx[0], bs0[0]);                                      \
    e[1] = fmaf((XV), wx[1], bs0[1]);                                      \
    e[2] = fmaf((XV), wx[2], bs0[2]);                                      \
    e[3] = fmaf((XV), wx[3], bs0[3]);                                      \
    e = mfma16(A0I0, B00, e); e = mfma16(A0S0, B00, e);                    \
    e = mfma16(A0I1, B01, e); e = mfma16(A0S1, B01, e);                    \
    float i0 = sigmoid_f(e[0]), f0 = sigmoid_f(e[1]);                      \
    float g0 = tanh_fast(e[2]), o0 = sigmoid_f(e[3]);                      \
    c0 = fmaf(f0, c0, i0 * g0);                                            \
    float h0v = o0 * tanh_fast(c0);                                        \
    hw[(P)][0][wrI] = packsplit(h0v);                                      \
    __syncthreads();                                                       \
    B00 = *(const half8*)&hw[(P)][0][rdI];                                 \
    B01 = *(const half8*)&hw[(P)][0][rdI + 16];                            \
    half8 B10 = *(const half8*)&hw[(P)^1][1][rdI];                         \
    half8 B11 = *(const half8*)&hw[(P)^1][1][rdI + 16];                    \
    f32x4 u = bias1;                                                       \
    u = mfma16(AHI0, B10, u); u = mfma16(AHS0, B10, u);                    \
    u = mfma16(AII0, B00, u); u = mfma16(AIS0, B00, u);                    \
    f32x4 v2 = {0.f, 0.f, 0.f, 0.f};                                       \
    v2 = mfma16(AHI1, B11, v2); v2 = mfma16(AHS1, B11, v2);                \
    v2 = mfma16(AII1, B01, v2); v2 = mfma16(AIS1, B01, v2);                \
    float i1 = sigmoid_f(u[0] + v2[0]), f1 = sigmoid_f(u[1] + v2[1]);      \
    float g1 = tanh_fast(u[2] + v2[2]), o1 = sigmoid_f(u[3] + v2[3]);      \
    c1 = fmaf(f1, c1, i1 * g1);                                            \
    h1v = o1 * tanh_fast(c1);                                              \
    hw[(P)][1][wrI] = packsplit(h1v);                                      \
  }

  const float4* xp4 = (const float4*)(x + (size_t)(b0 + col) * Tn);
  float4 xc = xp4[0];
  for (int T0 = 0; T0 < Tn; T0 += 4){
    int nidx = (T0 + 4 < Tn) ? (T0 >> 2) + 1 : (T0 >> 2);
    float4 xn = xp4[nidx];                    // prefetched a full quad ahead
    STEP(0, xc.x);
    STEP(1, xc.y);
    STEP(0, xc.z);
    STEP(1, xc.w);
    xc = xn;
  }
#undef STEP

  // ---- FC head: out[b0+c] = dot(h1_final[:,c], Wfc) + bfc ----
  __syncthreads();
  float* sc = (float*)&hw[0][0][0];
  sc[s*17 + col] = h1v;
  __syncthreads();
  if (tid < 16){
    float acc = bfc[0];
    #pragma unroll 8
    for (int k = 0; k < HSZ; ++k) acc = fmaf(sc[k*17 + tid], Wfc[k], acc);
    out[b0 + tid] = acc;
  }
}

extern "C" void kernel_launch(void* const* d_in, const int* in_sizes, int n_in,
                              void* d_out, int out_size, void* d_ws, size_t ws_size,
                              hipStream_t stream) {
  const float* x    = (const float*)d_in[0];
  const float* Wih0 = (const float*)d_in[1];
  const float* Whh0 = (const float*)d_in[2];
  const float* bih0 = (const float*)d_in[3];
  const float* bhh0 = (const float*)d_in[4];
  const float* Wih1 = (const float*)d_in[5];
  const float* Whh1 = (const float*)d_in[6];
  const float* bih1 = (const float*)d_in[7];
  const float* bhh1 = (const float*)d_in[8];
  const float* Wfc  = (const float*)d_in[9];
  const float* bfc  = (const float*)d_in[10];
  float* out = (float*)d_out;

  const int Tn = TLEN;
  const int B  = in_sizes[0] / Tn;     // x is (B, T, 1)

  dim3 block(512);
  dim3 grid(B / 16);
  hipLaunchKernelGGL(lstm2_mfma4, grid, block, 0, stream,
                     x, Wih0, Whh0, bih0, bhh0, Wih1, Whh1, bih1, bhh1,
                     Wfc, bfc, out, Tn);
}

// Round 5
// 537.567 us; speedup vs baseline: 4.4461x; 1.0724x over previous
//
#include <hip/hip_runtime.h>

#define HSZ  32
#define TLEN 1024
#define CS   36   // u32 stride per col in an h plane (144 B: 16B-aligned, even spread)

typedef _Float16 half8 __attribute__((ext_vector_type(8)));
typedef float    f32x4 __attribute__((ext_vector_type(4)));

__device__ __forceinline__ float rcp_f(float x){ return __builtin_amdgcn_rcpf(x); }
__device__ __forceinline__ float exp2_f(float x){ return __builtin_amdgcn_exp2f(x); }
#define LOG2E 1.442695040888963f
__device__ __forceinline__ float sigmoid_f(float x){ return rcp_f(1.0f + exp2_f(-LOG2E*x)); }
__device__ __forceinline__ float tanh_fast(float x){ return 1.0f - 2.0f*rcp_f(1.0f + exp2_f(2.0f*LOG2E*x)); }
__device__ __forceinline__ f32x4 mfma16(half8 a, half8 b, f32x4 c){
  return __builtin_amdgcn_mfma_f32_16x16x32_f16(a, b, c, 0, 0, 0);
}

// LDS-only barrier: drain lgkmcnt (ds_writes visible) WITHOUT draining vmcnt,
// so the x global prefetch stays in flight across step barriers.
// "memory" clobber: no LDS op may be reordered across it.
__device__ __forceinline__ void lds_barrier(){
  asm volatile("s_waitcnt lgkmcnt(0)\n\ts_barrier" ::: "memory");
}

// Split a f32 into (hi,lo) f16 pair packed in one u32 (hi in low 16 bits).
__device__ __forceinline__ unsigned int packsplit(float v){
  _Float16 hi = (_Float16)v;
  _Float16 lo = (_Float16)(v - (float)hi);
  unsigned short a = __builtin_bit_cast(unsigned short, hi);
  unsigned short b = __builtin_bit_cast(unsigned short, lo);
  return (unsigned int)a | ((unsigned int)b << 16);
}

// 8 waves = one 16-batch tile; wave w owns states 4w..4w+3 (permuted A-row trick:
// A tile-row r loads physical gate row 32*(r&3)+4w+(r>>2), so lane (g,col) D-regs
// j=0..3 are gates (i,f,g,o) of state s=4w+g -- whole quad in-lane, no gate LDS).
//
// EXACT interleaved split: h stored as u32 = (f16 hi, f16 lo). MFMA slot pairs:
//   A_I = (wh,wl) interleaved, A_S = (wl,wh) swapped.
//   mfma(A_I,B) + mfma(A_S,B) = sum_k (wh+wl)*(hh+hl)  -- exact split product.
// Per step: 12 MFMA, 4 ds_read_b128, 2 ds_write_b32, ONE lgkm-only barrier.
__global__ __launch_bounds__(512, 2) void lstm2_mfma5(
    const float* __restrict__ x,
    const float* __restrict__ Wih0, const float* __restrict__ Whh0,
    const float* __restrict__ bih0, const float* __restrict__ bhh0,
    const float* __restrict__ Wih1, const float* __restrict__ Whh1,
    const float* __restrict__ bih1, const float* __restrict__ bhh1,
    const float* __restrict__ Wfc,  const float* __restrict__ bfc,
    float* __restrict__ out, int Tn)
{
  __shared__ __align__(16) unsigned int hw[2][2][16*CS];  // [parity][layer][col*CS + k]

  const int tid = threadIdx.x;
  const int w   = tid >> 6;
  const int l   = tid & 63;
  const int col = l & 15;        // batch col == A tile-row index
  const int g   = l >> 4;        // k-group == D row-group
  const int s   = 4*w + g;       // state this lane owns
  const int b0  = blockIdx.x * 16;

  // ---- A fragments (interleaved + swapped), permuted rows ----
  const int prow = 32*(col & 3) + 4*w + (col >> 2);
  half8 A0I0, A0I1, A0S0, A0S1;   // Whh0
  half8 AII0, AII1, AIS0, AIS1;   // Wih1
  half8 AHI0, AHI1, AHS0, AHS1;   // Whh1
  {
    const float* rows[3] = { Whh0 + prow*HSZ, Wih1 + prow*HSZ, Whh1 + prow*HSZ };
    half8* I0[3] = { &A0I0, &AII0, &AHI0 };
    half8* I1[3] = { &A0I1, &AII1, &AHI1 };
    half8* S0[3] = { &A0S0, &AIS0, &AHS0 };
    half8* S1[3] = { &A0S1, &AIS1, &AHS1 };
    #pragma unroll
    for (int m3 = 0; m3 < 3; ++m3){
      #pragma unroll
      for (int H = 0; H < 2; ++H){
        half8& I = H ? *I1[m3] : *I0[m3];
        half8& S = H ? *S1[m3] : *S0[m3];
        #pragma unroll
        for (int m = 0; m < 4; ++m){
          float v = rows[m3][16*H + 4*g + m];
          _Float16 hi = (_Float16)v;
          _Float16 lo = (_Float16)(v - (float)hi);
          I[2*m] = hi; I[2*m+1] = lo;
          S[2*m] = lo; S[2*m+1] = hi;
        }
      }
    }
  }
  // D reg j = physical gate row 32j + s
  float wx[4], bs0[4];
  f32x4 bias1;
  #pragma unroll
  for (int j = 0; j < 4; ++j){
    int r   = 32*j + s;
    wx[j]   = Wih0[r];
    bs0[j]  = bih0[r] + bhh0[r];
    bias1[j]= bih1[r] + bhh1[r];
  }

  const int wrI = col*CS + s;        // u32 index for this lane's h write
  const int rdI = col*CS + 4*g;      // u32 index of b128 read (half 0); +16 for half 1

  for (int i = tid; i < 2*2*16*CS; i += 512) (&hw[0][0][0])[i] = 0u;
  __syncthreads();

  half8 B00 = {}; half8 B01 = {};    // h0(t-1) fragments, start at 0
  float c0 = 0.f, c1 = 0.f, h1v = 0.f;

#define STEP(P, XV)                                                        \
  {                                                                        \
    f32x4 e;                                                               \
    e[0] = fmaf((XV), wx[0], bs0[0]);                                      \
    e[1] = fmaf((XV), wx[1], bs0[1]);                                      \
    e[2] = fmaf((XV), wx[2], bs0[2]);                                      \
    e[3] = fmaf((XV), wx[3], bs0[3]);                                      \
    __builtin_amdgcn_s_setprio(1);                                         \
    e = mfma16(A0I0, B00, e); e = mfma16(A0S0, B00, e);                    \
    e = mfma16(A0I1, B01, e); e = mfma16(A0S1, B01, e);                    \
    __builtin_amdgcn_s_setprio(0);                                         \
    float i0 = sigmoid_f(e[0]), f0 = sigmoid_f(e[1]);                      \
    float g0 = tanh_fast(e[2]), o0 = sigmoid_f(e[3]);                      \
    c0 = fmaf(f0, c0, i0 * g0);                                            \
    float h0v = o0 * tanh_fast(c0);                                        \
    hw[(P)][0][wrI] = packsplit(h0v);                                      \
    lds_barrier();                                                         \
    B00 = *(const half8*)&hw[(P)][0][rdI];                                 \
    B01 = *(const half8*)&hw[(P)][0][rdI + 16];                            \
    half8 B10 = *(const half8*)&hw[(P)^1][1][rdI];                         \
    half8 B11 = *(const half8*)&hw[(P)^1][1][rdI + 16];                    \
    f32x4 u = bias1;                                                       \
    f32x4 v2 = {0.f, 0.f, 0.f, 0.f};                                       \
    __builtin_amdgcn_s_setprio(1);                                         \
    u = mfma16(AHI0, B10, u); u = mfma16(AHS0, B10, u);                    \
    v2 = mfma16(AHI1, B11, v2); v2 = mfma16(AHS1, B11, v2);                \
    u = mfma16(AII0, B00, u); u = mfma16(AIS0, B00, u);                    \
    v2 = mfma16(AII1, B01, v2); v2 = mfma16(AIS1, B01, v2);                \
    __builtin_amdgcn_s_setprio(0);                                         \
    float i1 = sigmoid_f(u[0] + v2[0]), f1 = sigmoid_f(u[1] + v2[1]);      \
    float g1 = tanh_fast(u[2] + v2[2]), o1 = sigmoid_f(u[3] + v2[3]);      \
    c1 = fmaf(f1, c1, i1 * g1);                                            \
    h1v = o1 * tanh_fast(c1);                                              \
    hw[(P)][1][wrI] = packsplit(h1v);                                      \
  }

  const float4* xp4 = (const float4*)(x + (size_t)(b0 + col) * Tn);
  float4 xc = xp4[0];
  for (int T0 = 0; T0 < Tn; T0 += 4){
    int nidx = (T0 + 4 < Tn) ? (T0 >> 2) + 1 : (T0 >> 2);
    float4 xn = xp4[nidx];                    // prefetched a full quad ahead
    STEP(0, xc.x);
    STEP(1, xc.y);
    STEP(0, xc.z);
    STEP(1, xc.w);
    xc = xn;
  }
#undef STEP

  // ---- FC head: out[b0+c] = dot(h1_final[:,c], Wfc) + bfc ----
  __syncthreads();
  float* sc = (float*)&hw[0][0][0];
  sc[s*17 + col] = h1v;
  __syncthreads();
  if (tid < 16){
    float acc = bfc[0];
    #pragma unroll 8
    for (int k = 0; k < HSZ; ++k) acc = fmaf(sc[k*17 + tid], Wfc[k], acc);
    out[b0 + tid] = acc;
  }
}

extern "C" void kernel_launch(void* const* d_in, const int* in_sizes, int n_in,
                              void* d_out, int out_size, void* d_ws, size_t ws_size,
                              hipStream_t stream) {
  const float* x    = (const float*)d_in[0];
  const float* Wih0 = (const float*)d_in[1];
  const float* Whh0 = (const float*)d_in[2];
  const float* bih0 = (const float*)d_in[3];
  const float* bhh0 = (const float*)d_in[4];
  const float* Wih1 = (const float*)d_in[5];
  const float* Whh1 = (const float*)d_in[6];
  const float* bih1 = (const float*)d_in[7];
  const float* bhh1 = (const float*)d_in[8];
  const float* Wfc  = (const float*)d_in[9];
  const float* bfc  = (const float*)d_in[10];
  float* out = (float*)d_out;

  const int Tn = TLEN;
  const int B  = in_sizes[0] / Tn;     // x is (B, T, 1)

  dim3 block(512);
  dim3 grid(B / 16);
  hipLaunchKernelGGL(lstm2_mfma5, grid, block, 0, stream,
                     x, Wih0, Whh0, bih0, bhh0, Wih1, Whh1, bih1, bhh1,
                     Wfc, bfc, out, Tn);
}